// Round 5
// baseline (258.919 us; speedup 1.0000x reference)
//
#include <hip/hip_runtime.h>

typedef __attribute__((ext_vector_type(8)))  short bf16x8;   // 8 bf16 in 4 VGPRs
typedef __attribute__((ext_vector_type(4)))  float f32x4;
typedef __attribute__((ext_vector_type(16))) float f32x16;
typedef __attribute__((ext_vector_type(8)))  unsigned short u16x8;

#define HW 4096
#define CDIM 256

__device__ __forceinline__ unsigned short f2bf(float f) {   // RTNE
    union { float f; unsigned u; } v; v.f = f;
    unsigned r = v.u + 0x7fffu + ((v.u >> 16) & 1u);
    return (unsigned short)(r >> 16);
}
__device__ __forceinline__ unsigned short truncbf(float f) { // truncation (P)
    union { float f; unsigned u; } v; v.f = f;
    return (unsigned short)(v.u >> 16);
}
__device__ __forceinline__ float bf2f(unsigned short u) {
    union { unsigned u; float f; } v; v.u = ((unsigned)u) << 16;
    return v.f;
}
// pack bf16(hi)|bf16(lo) — truncation via v_perm_b32
__device__ __forceinline__ unsigned pk2(float hi, float lo) {
    union { float f; unsigned u; } a, b; a.f = hi; b.f = lo;
    return __builtin_amdgcn_perm(a.u, b.u, 0x07060302u);
}
// async global->LDS, 16B per lane; LDS dest = wave-uniform base + lane*16
__device__ __forceinline__ void gl_lds16(const void* g, void* l) {
    __builtin_amdgcn_global_load_lds(
        (const __attribute__((address_space(1))) unsigned int*)(unsigned long long)g,
        (__attribute__((address_space(3))) unsigned int*)(unsigned int)(unsigned long long)l,
        16, 0, 0);
}

// ---------------------------------------------------------------------------
// Kernel 0: pack W (fp32) -> Wpk bf16 [inp][448 o][256 c] row-major. (r4, frozen)
// ---------------------------------------------------------------------------
__global__ __launch_bounds__(256) void wpack_kernel(
    const float* __restrict__ Wq1, const float* __restrict__ Wk1,
    const float* __restrict__ Wv1, const float* __restrict__ Wq2,
    const float* __restrict__ Wk2, const float* __restrict__ Wv2,
    unsigned short* __restrict__ Wpk)
{
    const int i  = blockIdx.x * 256 + threadIdx.x;     // 0..57343
    const int c4 = i & 63;
    const int r6 = i >> 6;                             // 0..895
    const int inp = r6 / 448;
    const int o   = r6 - inp * 448;
    const float* src;
    int orow;
    if (o < 64)       { src = inp ? Wq2 : Wq1; orow = o; }
    else if (o < 192) { src = inp ? Wk2 : Wk1; orow = o - 64; }
    else              { src = inp ? Wv2 : Wv1; orow = o - 192; }
    const float4 v = *(const float4*)(src + (size_t)orow * CDIM + c4 * 4);
    uint2 pkd; pkd.x = pk2(v.y, v.x); pkd.y = pk2(v.w, v.z);
    ((uint2*)Wpk)[i] = pkd;
}

// ---------------------------------------------------------------------------
// Kernel 1: projections. (r4, frozen) grid 1024: ntile(256 of 16 n) x inp x b.
// ---------------------------------------------------------------------------
__global__ __launch_bounds__(256) void proj_kernel(
    const float* __restrict__ in1, const float* __restrict__ in2,
    const float* __restrict__ bq1, const float* __restrict__ bk1,
    const float* __restrict__ bv1, const float* __restrict__ bq2,
    const float* __restrict__ bk2, const float* __restrict__ bv2,
    const unsigned short* __restrict__ Wpk,
    unsigned short* __restrict__ Qg, unsigned short* __restrict__ Kg,
    unsigned short* __restrict__ Vg)
{
    const int bid   = blockIdx.x;
    const int ntile = bid & 255;
    const int inp   = (bid >> 8) & 1;
    const int b     = bid >> 9;

    const float* X  = (inp ? in2 : in1) + (size_t)b * CDIM * HW;
    const float* bq = inp ? bq2 : bq1;
    const float* bk = inp ? bk2 : bk1;
    const float* bv = inp ? bv2 : bv1;
    const unsigned short* Wb = Wpk + (size_t)inp * 448 * CDIM;

    const int lane = threadIdx.x & 63;
    const int w    = threadIdx.x >> 6;
    const int l15  = lane & 15, quad = lane >> 4;
    const int n0   = ntile * 16;

    f32x4 acc[7];
#pragma unroll
    for (int i = 0; i < 7; ++i) acc[i] = (f32x4){0.f, 0.f, 0.f, 0.f};

    for (int kk = 0; kk < 8; ++kk) {
        const int ci0 = kk * 32 + quad * 8;
        const float* xp = X + (size_t)ci0 * HW + n0 + l15;
        float xv[8];
#pragma unroll
        for (int j = 0; j < 8; ++j) xv[j] = xp[(size_t)j * HW];
        union { bf16x8 v; unsigned u[4]; } xt;
#pragma unroll
        for (int j = 0; j < 4; ++j) xt.u[j] = pk2(xv[2 * j + 1], xv[2 * j]);
        const bf16x8 xf = xt.v;

#pragma unroll
        for (int os = 0; os < 7; ++os) {
            const int ob = w * 7 + os;
            const int og = ob * 16 + l15;
            const bf16x8 wf = *(const bf16x8*)(Wb + (size_t)og * CDIM + ci0);
            if (ob < 12)
                acc[os] = __builtin_amdgcn_mfma_f32_16x16x32_bf16(xf, wf, acc[os], 0, 0, 0);
            else
                acc[os] = __builtin_amdgcn_mfma_f32_16x16x32_bf16(wf, xf, acc[os], 0, 0, 0);
        }
    }

    const size_t qbase = (size_t)b * HW * 128;
    const size_t kbase = (size_t)(b * 2 + inp) * HW * 128;
    const size_t vbase = (size_t)(b * 2 + inp) * (size_t)CDIM * HW;
#pragma unroll
    for (int os = 0; os < 7; ++os) {
        const int ob = w * 7 + os;
        f32x4 d = acc[os];
        if (ob < 4) {
            const int o = ob * 16 + l15;
            const float bb = bq[o];
#pragma unroll
            for (int r = 0; r < 4; ++r) {
                const int n = n0 + quad * 4 + r;
                Qg[qbase + (size_t)n * 128 + 2 * o + inp] = f2bf(d[r] + bb);
            }
        } else if (ob < 12) {
            const int c = (ob - 4) * 16 + l15;
            const float bb = bk[c];
#pragma unroll
            for (int r = 0; r < 4; ++r) {
                const int n = n0 + quad * 4 + r;
                Kg[kbase + (size_t)n * 128 + c] = f2bf(d[r] + bb);
            }
        } else {
            const int c0 = (ob - 12) * 16 + quad * 4;
#pragma unroll
            for (int r = 0; r < 4; ++r) {
                const int n = n0 + l15;
                Vg[vbase + (size_t)(c0 + r) * HW + n] = f2bf(d[r] + bv[c0 + r]);
            }
        }
    }
}

// ---------------------------------------------------------------------------
// Kernel 2: streaming attention, software-pipelined: PV(mt-1) overlaps S(mt).
// grid 512, 2 blocks/CU. One barrier/iter (doubles as P handoff + async drain).
// ch-split exp (each ch-wave exps half of S); l accumulated via MFMA(ones,P).
// Unroll-by-2 makes all LDS offsets compile-time. Partials (O bf16, l f32)->ws.
// ---------------------------------------------------------------------------
__global__ __launch_bounds__(256, 2) void attn_kernel(
    const unsigned short* __restrict__ Qg, const unsigned short* __restrict__ Kg,
    const unsigned short* __restrict__ Vg,
    unsigned short* __restrict__ Op, float* __restrict__ Lp)
{
    __shared__ unsigned short kbuf[2][32 * 16 * 8];    // 8 KB each
    __shared__ unsigned short vbuf[2][256 * 4 * 8];    // 16 KB each
    __shared__ unsigned short pbuf[2][2][32 * 40];     // [par][ng][n:32][m:40]

    const int bid = blockIdx.x;
    const int set = (bid & 7) >> 1;
    const int att = set & 1, b = set >> 1;
    const int sub = ((bid >> 3) << 1) | (bid & 1);     // 0..127
    const int mh  = sub & 1, qt = sub >> 1;
    const int n0g = qt * 64;
    const int mbase = mh * 2048;
    const int tid = threadIdx.x;
    const int lane = tid & 63, w = tid >> 6;
    const int l31 = lane & 31, h = lane >> 5;
    const int ng = w >> 1, ch = w & 1;

    const unsigned short* Qb = Qg + (size_t)b * HW * 128;
    const unsigned short* Kb = Kg + (size_t)(b * 2 + att) * HW * 128;
    const unsigned short* Vb = Vg + (size_t)(b * 2 + att) * (size_t)CDIM * HW;

    // Q A-frags: A[n=lane&31][k = kk*16 + h*8 + j]
    bf16x8 aQ[8];
    {
        const int n = n0g + ng * 32 + l31;
#pragma unroll
        for (int kk = 0; kk < 8; ++kk)
            aQ[kk] = *(const bf16x8*)(Qb + (size_t)n * 128 + kk * 16 + h * 8);
    }

    f32x16 acc[4];
#pragma unroll
    for (int i = 0; i < 4; ++i)
#pragma unroll
        for (int r = 0; r < 16; ++r) acc[i][r] = 0.f;
    f32x16 lacc;
#pragma unroll
    for (int r = 0; r < 16; ++r) lacc[r] = 0.f;
    bf16x8 ones;
#pragma unroll
    for (int j = 0; j < 8; ++j) ones[j] = (short)0x3F80;   // bf16 1.0

    // loop-invariant LDS element indices
    int kidx[8];
#pragma unroll
    for (int kk = 0; kk < 8; ++kk)
        kidx[kk] = (l31 * 16 + ((kk * 2 + h) ^ (l31 & 15))) * 8;
    int vidx[4][2];
#pragma unroll
    for (int cf = 0; cf < 4; ++cf) {
        const int c = ch * 128 + cf * 32 + l31;
#pragma unroll
        for (int k2 = 0; k2 < 2; ++k2)
            vidx[cf][k2] = (c * 4 + ((k2 * 2 + h) ^ ((c >> 2) & 3))) * 8;
    }
    int pidx[2];
#pragma unroll
    for (int k2 = 0; k2 < 2; ++k2) pidx[k2] = l31 * 40 + k2 * 16 + h * 8;
    const int pwbase = (8 * ch + 4 * h) * 40 + l31;

    // per-lane staging addresses (m0-invariant parts)
    const unsigned short* ksrc[2]; unsigned short* kdst[2][2];
    const unsigned short* vsrc[4]; unsigned short* vdst[2][4];
#pragma unroll
    for (int t = 0; t < 2; ++t) {
        const int L = (t * 4 + w) * 64 + lane;
        const int ml = L >> 4, s = L & 15;
        const int g = s ^ (ml & 15);
        ksrc[t] = Kb + (size_t)ml * 128 + g * 8;
        kdst[0][t] = &kbuf[0][L * 8]; kdst[1][t] = &kbuf[1][L * 8];
    }
#pragma unroll
    for (int t = 0; t < 4; ++t) {
        const int L = (t * 4 + w) * 64 + lane;
        const int c = L >> 2, s = L & 3;
        const int g = s ^ ((c >> 2) & 3);
        vsrc[t] = Vb + (size_t)c * HW + g * 8;
        vdst[0][t] = &vbuf[0][L * 8]; vdst[1][t] = &vbuf[1][L * 8];
    }

    auto stageK = [&](int mt, int bs) {
        const int m0 = mbase + mt * 32;
#pragma unroll
        for (int t = 0; t < 2; ++t) gl_lds16(ksrc[t] + (size_t)m0 * 128, kdst[bs][t]);
    };
    auto stageV = [&](int mt, int bs) {
        const int m0 = mbase + mt * 32;
#pragma unroll
        for (int t = 0; t < 4; ++t) gl_lds16(vsrc[t] + m0, vdst[bs][t]);
    };

    // PV for tile whose V sits in vbuf[vb], P in pbuf[pb]. One pbuf load
    // serves both the B-frag of the O-MFMA and of the l-MFMA.
    auto pv = [&](int vb, int pb) {
        const unsigned short* pc = &pbuf[pb][ng][0];
        bf16x8 pf[2];
#pragma unroll
        for (int k2 = 0; k2 < 2; ++k2)
            pf[k2] = *(const bf16x8*)&pc[pidx[k2]];
        lacc = __builtin_amdgcn_mfma_f32_32x32x16_bf16(ones, pf[0], lacc, 0, 0, 0);
        lacc = __builtin_amdgcn_mfma_f32_32x32x16_bf16(ones, pf[1], lacc, 0, 0, 0);
#pragma unroll
        for (int cf = 0; cf < 4; ++cf) {
#pragma unroll
            for (int k2 = 0; k2 < 2; ++k2) {
                const bf16x8 vf = *(const bf16x8*)&vbuf[vb][vidx[cf][k2]];
                acc[cf] = __builtin_amdgcn_mfma_f32_32x32x16_bf16(vf, pf[k2], acc[cf], 0, 0, 0);
            }
        }
    };

    auto body = [&](int mt, int cur) {
        __syncthreads();                 // drains async stages; P(mt-1) visible
        if (mt < 63) stageK(mt + 1, cur ^ 1);
        stageV(mt, cur);

        // S(mt): two independent 4-chains
        f32x16 sa, sb;
#pragma unroll
        for (int r = 0; r < 16; ++r) { sa[r] = 0.f; sb[r] = 0.f; }
#pragma unroll
        for (int kk = 0; kk < 4; ++kk) {
            const bf16x8 kf = *(const bf16x8*)&kbuf[cur][kidx[kk]];
            sa = __builtin_amdgcn_mfma_f32_32x32x16_bf16(aQ[kk], kf, sa, 0, 0, 0);
        }
#pragma unroll
        for (int kk = 4; kk < 8; ++kk) {
            const bf16x8 kf = *(const bf16x8*)&kbuf[cur][kidx[kk]];
            sb = __builtin_amdgcn_mfma_f32_32x32x16_bf16(aQ[kk], kf, sb, 0, 0, 0);
        }

        if (mt > 0) pv(cur ^ 1, cur ^ 1);   // PV(mt-1), independent of S-chain

        // ch-split exp (8 regs/wave) + 8 scalar P writes (no max-sub; |s|<~6.5)
        unsigned short* pc = &pbuf[cur][ng][0];
#pragma unroll
        for (int i = 0; i < 3 + 1; ++i) {
            const int r0 = ch * 4 + i;
            const int r1 = ch * 4 + 8 + i;
            pc[pwbase + i * 40]        = truncbf(__expf(sa[r0] + sb[r0]));
            pc[pwbase + (16 + i) * 40] = truncbf(__expf(sa[r1] + sb[r1]));
        }
    };

    stageK(0, 0);
    for (int mt = 0; mt < 64; mt += 2) {
        body(mt, 0);
        body(mt + 1, 1);
    }
    __syncthreads();
    pv(1, 1);                            // PV(63)

    const int nn = n0g + ng * 32 + l31;
    if (ch == 0 && h == 0) Lp[(size_t)(mh * 4 + set) * HW + nn] = lacc[0];

    const size_t obase = (size_t)(mh * 4 + set) * CDIM * HW;
#pragma unroll
    for (int cf = 0; cf < 4; ++cf) {
#pragma unroll
        for (int r = 0; r < 16; ++r) {
            const int c = ch * 128 + cf * 32 + (r & 3) + 8 * (r >> 2) + 4 * h;
            Op[obase + (size_t)c * HW + nn] = f2bf(acc[cf][r]);
        }
    }
}

// ---------------------------------------------------------------------------
// Kernel 3: combine partials: out = g*(O0+O1)/(l0+l1) + input. (r4, frozen)
// ---------------------------------------------------------------------------
__global__ __launch_bounds__(256) void combine_kernel(
    const unsigned short* __restrict__ Op, const float* __restrict__ Lp,
    const float* __restrict__ in1, const float* __restrict__ in2,
    const float* __restrict__ gamma_p, float* __restrict__ out)
{
    const size_t i8 = ((size_t)blockIdx.x * 256 + threadIdx.x) * 8;
    const int oset = (int)(i8 >> 20);          // att*2 + b
    const int att = oset >> 1, b = oset & 1;
    const int pset = b * 2 + att;
    const size_t rem = i8 & 1048575u;          // c*HW + n
    const int n = (int)(i8 & 4095);

    const u16x8 o0 = *(const u16x8*)(Op + ((size_t)pset << 20) + rem);
    const u16x8 o1 = *(const u16x8*)(Op + ((size_t)pset << 20) + rem + ((size_t)4 << 20));
    const f32x4 la0 = *(const f32x4*)(Lp + (size_t)pset * HW + n);
    const f32x4 la1 = *(const f32x4*)(Lp + (size_t)pset * HW + n + 4);
    const f32x4 lb0 = *(const f32x4*)(Lp + (size_t)(4 + pset) * HW + n);
    const f32x4 lb1 = *(const f32x4*)(Lp + (size_t)(4 + pset) * HW + n + 4);
    const float* inb = (att ? in2 : in1) + (size_t)b * CDIM * HW + rem;
    const float g = *gamma_p;

    const f32x4 iv0 = *(const f32x4*)(inb);
    const f32x4 iv1 = *(const f32x4*)(inb + 4);
    f32x4 r0, r1;
#pragma unroll
    for (int j = 0; j < 4; ++j) {
        const float ov = bf2f((unsigned short)o0[j]) + bf2f((unsigned short)o1[j]);
        r0[j] = g * ov / (la0[j] + lb0[j]) + iv0[j];
    }
#pragma unroll
    for (int j = 0; j < 4; ++j) {
        const float ov = bf2f((unsigned short)o0[j + 4]) + bf2f((unsigned short)o1[j + 4]);
        r1[j] = g * ov / (la1[j] + lb1[j]) + iv1[j];
    }
    *(f32x4*)(out + i8) = r0;
    *(f32x4*)(out + i8 + 4) = r1;
}

extern "C" void kernel_launch(void* const* d_in, const int* in_sizes, int n_in,
                              void* d_out, int out_size, void* d_ws, size_t ws_size,
                              hipStream_t stream) {
    const float* in1 = (const float*)d_in[0];
    const float* in2 = (const float*)d_in[1];
    const float* Wq1 = (const float*)d_in[2];  const float* bq1 = (const float*)d_in[3];
    const float* Wk1 = (const float*)d_in[4];  const float* bk1 = (const float*)d_in[5];
    const float* Wv1 = (const float*)d_in[6];  const float* bv1 = (const float*)d_in[7];
    const float* Wq2 = (const float*)d_in[8];  const float* bq2 = (const float*)d_in[9];
    const float* Wk2 = (const float*)d_in[10]; const float* bk2 = (const float*)d_in[11];
    const float* Wv2 = (const float*)d_in[12]; const float* bv2 = (const float*)d_in[13];
    const float* gamma = (const float*)d_in[14];

    unsigned short* Qg = (unsigned short*)d_ws;                 // [2][4096 n][128 c]
    unsigned short* Kg = Qg + (size_t)2 * HW * 128;             // [4][4096 m][128 c]
    unsigned short* Vg = Kg + (size_t)4 * HW * 128;             // [4][256 c][4096 m]
    unsigned short* Op = Vg + (size_t)4 * CDIM * HW;            // [2 mh][4 set][256 c][4096 n] bf16
    float*          Lp = (float*)(Op + (size_t)8 * CDIM * HW);  // [2 mh][4 set][4096 n] f32
    unsigned short* Wpk = Op;   // aliases Op: live only wpack->proj, dead before attn

    wpack_kernel<<<224, 256, 0, stream>>>(Wq1, Wk1, Wv1, Wq2, Wk2, Wv2, Wpk);
    proj_kernel<<<1024, 256, 0, stream>>>(in1, in2, bq1, bk1, bv1, bq2, bk2, bv2,
                                          Wpk, Qg, Kg, Vg);
    attn_kernel<<<512, 256, 0, stream>>>(Qg, Kg, Vg, Op, Lp);
    combine_kernel<<<2048, 256, 0, stream>>>(Op, Lp, in1, in2, gamma, (float*)d_out);
}

// Round 6
// 219.894 us; speedup vs baseline: 1.1775x; 1.1775x over previous
//
#include <hip/hip_runtime.h>

typedef __attribute__((ext_vector_type(8)))  short bf16x8;   // 8 bf16 in 4 VGPRs
typedef __attribute__((ext_vector_type(4)))  float f32x4;
typedef __attribute__((ext_vector_type(16))) float f32x16;
typedef __attribute__((ext_vector_type(8)))  unsigned short u16x8;

#define HW 4096
#define CDIM 256

__device__ __forceinline__ unsigned short f2bf(float f) {   // RTNE
    union { float f; unsigned u; } v; v.f = f;
    unsigned r = v.u + 0x7fffu + ((v.u >> 16) & 1u);
    return (unsigned short)(r >> 16);
}
__device__ __forceinline__ unsigned short truncbf(float f) { // truncation (P)
    union { float f; unsigned u; } v; v.f = f;
    return (unsigned short)(v.u >> 16);
}
__device__ __forceinline__ float bf2f(unsigned short u) {
    union { unsigned u; float f; } v; v.u = ((unsigned)u) << 16;
    return v.f;
}
// pack bf16(hi)|bf16(lo) — truncation via v_perm_b32
__device__ __forceinline__ unsigned pk2(float hi, float lo) {
    union { float f; unsigned u; } a, b; a.f = hi; b.f = lo;
    return __builtin_amdgcn_perm(a.u, b.u, 0x07060302u);
}
// async global->LDS, 16B per lane; LDS dest = wave-uniform base + lane*16
__device__ __forceinline__ void gl_lds16(const void* g, void* l) {
    __builtin_amdgcn_global_load_lds(
        (const __attribute__((address_space(1))) unsigned int*)(unsigned long long)g,
        (__attribute__((address_space(3))) unsigned int*)(unsigned int)(unsigned long long)l,
        16, 0, 0);
}

// ---------------------------------------------------------------------------
// Kernel 0: pack W (fp32) -> Wpk bf16 [inp][448 o][256 c] row-major. (frozen)
// ---------------------------------------------------------------------------
__global__ __launch_bounds__(256) void wpack_kernel(
    const float* __restrict__ Wq1, const float* __restrict__ Wk1,
    const float* __restrict__ Wv1, const float* __restrict__ Wq2,
    const float* __restrict__ Wk2, const float* __restrict__ Wv2,
    unsigned short* __restrict__ Wpk)
{
    const int i  = blockIdx.x * 256 + threadIdx.x;     // 0..57343
    const int c4 = i & 63;
    const int r6 = i >> 6;                             // 0..895
    const int inp = r6 / 448;
    const int o   = r6 - inp * 448;
    const float* src;
    int orow;
    if (o < 64)       { src = inp ? Wq2 : Wq1; orow = o; }
    else if (o < 192) { src = inp ? Wk2 : Wk1; orow = o - 64; }
    else              { src = inp ? Wv2 : Wv1; orow = o - 192; }
    const float4 v = *(const float4*)(src + (size_t)orow * CDIM + c4 * 4);
    uint2 pkd; pkd.x = pk2(v.y, v.x); pkd.y = pk2(v.w, v.z);
    ((uint2*)Wpk)[i] = pkd;
}

// ---------------------------------------------------------------------------
// Kernel 1: projections, v6. grid 512: ntile(128 of 32 n) x inp(2) x b(2).
// X staged to LDS as bf16 pairs [n:32][ci-pairs:128 u32], 16B chunks XOR-
// swizzled (chunk c of row n at slot c^(n&7)) -> each MFMA X-frag is one
// conflict-free ds_read_b128. Coalesced float4 global loads along n.
// ---------------------------------------------------------------------------
__global__ __launch_bounds__(256) void proj_kernel(
    const float* __restrict__ in1, const float* __restrict__ in2,
    const float* __restrict__ bq1, const float* __restrict__ bk1,
    const float* __restrict__ bv1, const float* __restrict__ bq2,
    const float* __restrict__ bk2, const float* __restrict__ bv2,
    const unsigned short* __restrict__ Wpk,
    unsigned short* __restrict__ Qg, unsigned short* __restrict__ Kg,
    unsigned short* __restrict__ Vg)
{
    __shared__ unsigned xb[32 * 128];   // 16 KB: [n][128 ci-pair u32], swizzled

    const int bid   = blockIdx.x;
    const int ntile = bid & 127;
    const int inp   = (bid >> 7) & 1;
    const int b     = bid >> 8;

    const float* X  = (inp ? in2 : in1) + (size_t)b * CDIM * HW;
    const float* bq = inp ? bq2 : bq1;
    const float* bk = inp ? bk2 : bk1;
    const float* bv = inp ? bv2 : bv1;
    const unsigned short* Wb = Wpk + (size_t)inp * 448 * CDIM;

    const int tid  = threadIdx.x;
    const int lane = tid & 63;
    const int w    = tid >> 6;
    const int l15  = lane & 15, quad = lane >> 4;
    const int n0   = ntile * 32;

    // ---- stage X -> LDS (bf16 pairs, transposed to [n][ci]) ----
#pragma unroll
    for (int t = 0; t < 4; ++t) {
        const int idx = t * 256 + tid;       // 0..1023
        const int cp  = idx >> 3;            // ci-pair 0..127
        const int n4  = idx & 7;             // float4 index along n
        const float* p0 = X + (size_t)(cp * 2) * HW + n0 + n4 * 4;
        const float4 a = *(const float4*)p0;
        const float4 bb = *(const float4*)(p0 + HW);
        const float av[4] = {a.x, a.y, a.z, a.w};
        const float bv4[4] = {bb.x, bb.y, bb.z, bb.w};
#pragma unroll
        for (int r = 0; r < 4; ++r) {
            const int n = n4 * 4 + r;
            xb[n * 128 + (((cp >> 2) ^ (n & 7)) << 2) + (cp & 3)] = pk2(bv4[r], av[r]);
        }
    }
    __syncthreads();

    f32x4 acc[7][2];
#pragma unroll
    for (int i = 0; i < 7; ++i)
#pragma unroll
        for (int j = 0; j < 2; ++j) acc[i][j] = (f32x4){0.f, 0.f, 0.f, 0.f};

#pragma unroll
    for (int kk = 0; kk < 8; ++kk) {
        bf16x8 xf[2];
#pragma unroll
        for (int ns = 0; ns < 2; ++ns) {
            const int nrow = ns * 16 + l15;
            xf[ns] = *(const bf16x8*)&xb[nrow * 128 + (((kk * 4 + quad) ^ (nrow & 7)) << 2)];
        }
#pragma unroll
        for (int os = 0; os < 7; ++os) {
            const int ob = w * 7 + os;
            const int og = ob * 16 + l15;
            const bf16x8 wf = *(const bf16x8*)(Wb + (size_t)og * CDIM + kk * 32 + quad * 8);
            if (ob < 12) {   // Q,K: Out^T -> A = X-frag, B = W-frag
#pragma unroll
                for (int ns = 0; ns < 2; ++ns)
                    acc[os][ns] = __builtin_amdgcn_mfma_f32_16x16x32_bf16(xf[ns], wf, acc[os][ns], 0, 0, 0);
            } else {         // V: Out -> A = W-frag, B = X-frag
#pragma unroll
                for (int ns = 0; ns < 2; ++ns)
                    acc[os][ns] = __builtin_amdgcn_mfma_f32_16x16x32_bf16(wf, xf[ns], acc[os][ns], 0, 0, 0);
            }
        }
    }

    const size_t qbase = (size_t)b * HW * 128;
    const size_t kbase = (size_t)(b * 2 + inp) * HW * 128;
    const size_t vbase = (size_t)(b * 2 + inp) * (size_t)CDIM * HW;
#pragma unroll
    for (int os = 0; os < 7; ++os) {
        const int ob = w * 7 + os;
        if (ob < 4) {
            const int o = ob * 16 + l15;
            const float bb = bq[o];
#pragma unroll
            for (int ns = 0; ns < 2; ++ns) {
                const f32x4 d = acc[os][ns];
#pragma unroll
                for (int r = 0; r < 4; ++r) {
                    const int n = n0 + ns * 16 + quad * 4 + r;
                    Qg[qbase + (size_t)n * 128 + 2 * o + inp] = f2bf(d[r] + bb);
                }
            }
        } else if (ob < 12) {
            const int c = (ob - 4) * 16 + l15;
            const float bb = bk[c];
#pragma unroll
            for (int ns = 0; ns < 2; ++ns) {
                const f32x4 d = acc[os][ns];
#pragma unroll
                for (int r = 0; r < 4; ++r) {
                    const int n = n0 + ns * 16 + quad * 4 + r;
                    Kg[kbase + (size_t)n * 128 + c] = f2bf(d[r] + bb);
                }
            }
        } else {
            const int c0 = (ob - 12) * 16 + quad * 4;
#pragma unroll
            for (int ns = 0; ns < 2; ++ns) {
                const f32x4 d = acc[os][ns];
#pragma unroll
                for (int r = 0; r < 4; ++r) {
                    const int n = n0 + ns * 16 + l15;
                    Vg[vbase + (size_t)(c0 + r) * HW + n] = f2bf(d[r] + bv[c0 + r]);
                }
            }
        }
    }
}

// ---------------------------------------------------------------------------
// Kernel 2: streaming attention (r4 body, verbatim — known 116 µs).
// grid 512, 2 blocks/CU, m-half split; wave-private P; 1 barrier/iter;
// K/V double-buffered via async global_load_lds staged one tile ahead.
// ---------------------------------------------------------------------------
__global__ __launch_bounds__(256) void attn_kernel(
    const unsigned short* __restrict__ Qg, const unsigned short* __restrict__ Kg,
    const unsigned short* __restrict__ Vg,
    unsigned short* __restrict__ Op, float* __restrict__ Lp)
{
    __shared__ unsigned short kbuf[2][32 * 16 * 8];
    __shared__ unsigned short vbuf[2][256 * 4 * 8];
    __shared__ unsigned short pbuf[4][32 * 40];
    __shared__ float lbuf[4][32];

    const int bid = blockIdx.x;
    const int set = (bid & 7) >> 1;
    const int att = set & 1, b = set >> 1;
    const int sub = ((bid >> 3) << 1) | (bid & 1);   // 0..127
    const int mh  = sub & 1, qt = sub >> 1;
    const int n0g = qt * 64;
    const int mbase = mh * 2048;
    const int tid = threadIdx.x;
    const int lane = tid & 63, w = tid >> 6;
    const int l31 = lane & 31, h = lane >> 5;
    const int ng = w >> 1, ch = w & 1;

    const unsigned short* Qb = Qg + (size_t)b * HW * 128;
    const unsigned short* Kb = Kg + (size_t)(b * 2 + att) * HW * 128;
    const unsigned short* Vb = Vg + (size_t)(b * 2 + att) * (size_t)CDIM * HW;

    bf16x8 aQ[8];
    {
        const int n = n0g + ng * 32 + l31;
#pragma unroll
        for (int kk = 0; kk < 8; ++kk)
            aQ[kk] = *(const bf16x8*)(Qb + (size_t)n * 128 + kk * 16 + h * 8);
    }

    f32x16 acc[4];
#pragma unroll
    for (int i = 0; i < 4; ++i)
#pragma unroll
        for (int r = 0; r < 16; ++r) acc[i][r] = 0.f;
    float lsum[16];
#pragma unroll
    for (int r = 0; r < 16; ++r) lsum[r] = 0.f;

    const unsigned short* ksrc[2]; unsigned short* kdst[2][2];
    const unsigned short* vsrc[4]; unsigned short* vdst[2][4];
#pragma unroll
    for (int t = 0; t < 2; ++t) {
        const int L = (t * 4 + w) * 64 + lane;
        const int ml = L >> 4, s = L & 15;
        const int g = s ^ (ml & 15);
        ksrc[t] = Kb + (size_t)ml * 128 + g * 8;
        kdst[0][t] = &kbuf[0][L * 8]; kdst[1][t] = &kbuf[1][L * 8];
    }
#pragma unroll
    for (int t = 0; t < 4; ++t) {
        const int L = (t * 4 + w) * 64 + lane;
        const int c = L >> 2, s = L & 3;
        const int g = s ^ ((c >> 2) & 3);
        vsrc[t] = Vb + (size_t)c * HW + g * 8;
        vdst[0][t] = &vbuf[0][L * 8]; vdst[1][t] = &vbuf[1][L * 8];
    }

    auto stage = [&](int mt, int bs) {
        const int m0 = mbase + mt * 32;
#pragma unroll
        for (int t = 0; t < 2; ++t) gl_lds16(ksrc[t] + (size_t)m0 * 128, kdst[bs][t]);
#pragma unroll
        for (int t = 0; t < 4; ++t) gl_lds16(vsrc[t] + m0, vdst[bs][t]);
    };

    stage(0, 0);

    unsigned short* pw = pbuf[w];

    for (int mt = 0; mt < 64; ++mt) {
        __syncthreads();                    // drains stage(mt); prev reads done
        if (mt + 1 < 64) stage(mt + 1, (mt + 1) & 1);
        const int cur = mt & 1;

        f32x16 sa, sb;
#pragma unroll
        for (int r = 0; r < 16; ++r) { sa[r] = 0.f; sb[r] = 0.f; }
#pragma unroll
        for (int kk = 0; kk < 4; ++kk) {
            bf16x8 bK = *(const bf16x8*)&kbuf[cur][(l31 * 16 + ((kk * 2 + h) ^ (l31 & 15))) * 8];
            sa = __builtin_amdgcn_mfma_f32_32x32x16_bf16(aQ[kk], bK, sa, 0, 0, 0);
        }
#pragma unroll
        for (int kk = 4; kk < 8; ++kk) {
            bf16x8 bK = *(const bf16x8*)&kbuf[cur][(l31 * 16 + ((kk * 2 + h) ^ (l31 & 15))) * 8];
            sb = __builtin_amdgcn_mfma_f32_32x32x16_bf16(aQ[kk], bK, sb, 0, 0, 0);
        }

#pragma unroll
        for (int r = 0; r < 16; ++r) {
            const float p = __expf(sa[r] + sb[r]);
            lsum[r] += p;
            pw[((r & 3) + 8 * (r >> 2) + 4 * h) * 40 + l31] = truncbf(p);
        }

        bf16x8 bP[2];
#pragma unroll
        for (int k2 = 0; k2 < 2; ++k2)
            bP[k2] = *(const bf16x8*)&pw[l31 * 40 + k2 * 16 + h * 8];
#pragma unroll
        for (int cf = 0; cf < 4; ++cf) {
            const int c = ch * 128 + cf * 32 + l31;
#pragma unroll
            for (int k2 = 0; k2 < 2; ++k2) {
                bf16x8 aV = *(const bf16x8*)&vbuf[cur][(c * 4 + ((k2 * 2 + h) ^ ((c >> 2) & 3))) * 8];
                acc[cf] = __builtin_amdgcn_mfma_f32_32x32x16_bf16(aV, bP[k2], acc[cf], 0, 0, 0);
            }
        }
    }

#pragma unroll
    for (int off = 1; off < 32; off <<= 1)
#pragma unroll
        for (int r = 0; r < 16; ++r) lsum[r] += __shfl_xor(lsum[r], off, 64);
    if (l31 == 0) {
#pragma unroll
        for (int r = 0; r < 16; ++r)
            lbuf[w][(r & 3) + 8 * (r >> 2) + 4 * h] = lsum[r];
    }

    const int nn = n0g + ng * 32 + l31;
    if (ch == 0) Lp[(size_t)(mh * 4 + set) * HW + nn] = lbuf[w][l31];

    const size_t obase = (size_t)(mh * 4 + set) * CDIM * HW;
#pragma unroll
    for (int cf = 0; cf < 4; ++cf) {
#pragma unroll
        for (int r = 0; r < 16; ++r) {
            const int c = ch * 128 + cf * 32 + (r & 3) + 8 * (r >> 2) + 4 * h;
            Op[obase + (size_t)c * HW + nn] = f2bf(acc[cf][r]);
        }
    }
}

// ---------------------------------------------------------------------------
// Kernel 3: combine partials: out = g*(O0+O1)/(l0+l1) + input. (frozen)
// ---------------------------------------------------------------------------
__global__ __launch_bounds__(256) void combine_kernel(
    const unsigned short* __restrict__ Op, const float* __restrict__ Lp,
    const float* __restrict__ in1, const float* __restrict__ in2,
    const float* __restrict__ gamma_p, float* __restrict__ out)
{
    const size_t i8 = ((size_t)blockIdx.x * 256 + threadIdx.x) * 8;
    const int oset = (int)(i8 >> 20);          // att*2 + b
    const int att = oset >> 1, b = oset & 1;
    const int pset = b * 2 + att;
    const size_t rem = i8 & 1048575u;          // c*HW + n
    const int n = (int)(i8 & 4095);

    const u16x8 o0 = *(const u16x8*)(Op + ((size_t)pset << 20) + rem);
    const u16x8 o1 = *(const u16x8*)(Op + ((size_t)pset << 20) + rem + ((size_t)4 << 20));
    const f32x4 la0 = *(const f32x4*)(Lp + (size_t)pset * HW + n);
    const f32x4 la1 = *(const f32x4*)(Lp + (size_t)pset * HW + n + 4);
    const f32x4 lb0 = *(const f32x4*)(Lp + (size_t)(4 + pset) * HW + n);
    const f32x4 lb1 = *(const f32x4*)(Lp + (size_t)(4 + pset) * HW + n + 4);
    const float* inb = (att ? in2 : in1) + (size_t)b * CDIM * HW + rem;
    const float g = *gamma_p;

    const f32x4 iv0 = *(const f32x4*)(inb);
    const f32x4 iv1 = *(const f32x4*)(inb + 4);
    f32x4 r0, r1;
#pragma unroll
    for (int j = 0; j < 4; ++j) {
        const float ov = bf2f((unsigned short)o0[j]) + bf2f((unsigned short)o1[j]);
        r0[j] = g * ov / (la0[j] + lb0[j]) + iv0[j];
    }
#pragma unroll
    for (int j = 0; j < 4; ++j) {
        const float ov = bf2f((unsigned short)o0[j + 4]) + bf2f((unsigned short)o1[j + 4]);
        r1[j] = g * ov / (la1[j] + lb1[j]) + iv1[j];
    }
    *(f32x4*)(out + i8) = r0;
    *(f32x4*)(out + i8 + 4) = r1;
}

extern "C" void kernel_launch(void* const* d_in, const int* in_sizes, int n_in,
                              void* d_out, int out_size, void* d_ws, size_t ws_size,
                              hipStream_t stream) {
    const float* in1 = (const float*)d_in[0];
    const float* in2 = (const float*)d_in[1];
    const float* Wq1 = (const float*)d_in[2];  const float* bq1 = (const float*)d_in[3];
    const float* Wk1 = (const float*)d_in[4];  const float* bk1 = (const float*)d_in[5];
    const float* Wv1 = (const float*)d_in[6];  const float* bv1 = (const float*)d_in[7];
    const float* Wq2 = (const float*)d_in[8];  const float* bq2 = (const float*)d_in[9];
    const float* Wk2 = (const float*)d_in[10]; const float* bk2 = (const float*)d_in[11];
    const float* Wv2 = (const float*)d_in[12]; const float* bv2 = (const float*)d_in[13];
    const float* gamma = (const float*)d_in[14];

    unsigned short* Qg = (unsigned short*)d_ws;                 // [2][4096 n][128 c]
    unsigned short* Kg = Qg + (size_t)2 * HW * 128;             // [4][4096 m][128 c]
    unsigned short* Vg = Kg + (size_t)4 * HW * 128;             // [4][256 c][4096 m]
    unsigned short* Op = Vg + (size_t)4 * CDIM * HW;            // [2 mh][4 set][256 c][4096 n] bf16
    float*          Lp = (float*)(Op + (size_t)8 * CDIM * HW);  // [2 mh][4 set][4096 n] f32
    unsigned short* Wpk = Op;   // aliases Op: live only wpack->proj, dead before attn

    wpack_kernel<<<224, 256, 0, stream>>>(Wq1, Wk1, Wv1, Wq2, Wk2, Wv2, Wpk);
    proj_kernel<<<512, 256, 0, stream>>>(in1, in2, bq1, bk1, bv1, bq2, bk2, bv2,
                                         Wpk, Qg, Kg, Vg);
    attn_kernel<<<512, 256, 0, stream>>>(Qg, Kg, Vg, Op, Lp);
    combine_kernel<<<2048, 256, 0, stream>>>(Op, Lp, in1, in2, gamma, (float*)d_out);
}